// Round 14
// baseline (114.439 us; speedup 1.0000x reference)
//
#include <hip/hip_runtime.h>

// ContactMapHead on MI355X — round 14: 64x64 tiles on both kernels (better
// FMA:staging ratio at unchanged occupancy). r8→r13 established occupancy
// (gemm 8 waves/CU via K-split-4); this round shrinks staging/fixed overhead.
// logits[b, p(i,j)] = h_i^T W h_j + b, p(i,j) = i*(1023-i)/2 + (j-i-1).
//
//   K1 gemm_g: out[:]=bias prologue; G[s][b] = H[b] @ W (K-quarter s)
//              (512 blocks x 256 thr: 8n x 8m x (2b x 4s), tile 64x64, micro 4x4)
//   K2 pair:   out += triu((G0+G1+G2+G3)[b] @ H[b]^T)
//              (576 blocks x 256 thr: 36 triu 64x64-tiles x 2b x 8 ksplit, atomicAdd)

#define LSEQ 512
#define HDIM 512
#define NPAIR 130816     // 512*511/2
#define KT 32
#define PADT 68          // 68*4 = 272 B row stride (16B-aligned for b128)
#define GELEMS (2 * LSEQ * HDIM)   // floats per G partial buffer (both batches)

// ---------------- K1: out=bias prologue + G[s][b] = H[b] @ W (K-quarter s) ----------------
__global__ __launch_bounds__(256)
void gemm_g(const float* __restrict__ hid, const float* __restrict__ W,
            const float* __restrict__ bias, float* __restrict__ G4,
            float* __restrict__ out) {
    // bias prologue: 512 blocks x 256 thr = 131072 threads cover 65408 float4
    {
        const int bid = (blockIdx.z * 8 + blockIdx.y) * 8 + blockIdx.x;
        const int i = bid * 256 + threadIdx.x;
        if (i < (2 * NPAIR) / 4) {
            const float bb = bias[0];
            ((float4*)out)[i] = make_float4(bb, bb, bb, bb);
        }
    }

    __shared__ float As[KT][PADT];   // k-major: As[k][m'], m-width 64
    __shared__ float Bs[KT][PADT];   // k-major: Bs[k][n'], n-width 64
    const int b  = blockIdx.z >> 2;          // batch
    const int s  = blockIdx.z & 3;           // K-quarter: k in [s*128, s*128+128)
    const int m0 = blockIdx.y * 64;
    const int n0 = blockIdx.x * 64;
    const int t  = threadIdx.x;
    const int tx = t & 15, ty = t >> 4;      // 16 x 16 thread grid, 4x4 micro
    const float* A = hid + b * (LSEQ * HDIM);

    float acc[4][4] = {};
    for (int k0 = s * 128; k0 < s * 128 + 128; k0 += KT) {
        #pragma unroll
        for (int l = 0; l < 2; ++l) {        // stage A: 64 rows x 32 k, transpose
            const int idx = t + l * 256;
            const int r = idx >> 3, c4 = (idx & 7) << 2;
            float4 va = *(const float4*)&A[(m0 + r) * HDIM + k0 + c4];
            As[c4 + 0][r] = va.x; As[c4 + 1][r] = va.y;
            As[c4 + 2][r] = va.z; As[c4 + 3][r] = va.w;
        }
        #pragma unroll
        for (int l = 0; l < 2; ++l) {        // stage B: 32 k-rows x 64 n (natural)
            const int idx = t + l * 256;
            const int r = idx >> 4, c4 = (idx & 15) << 2;
            *(float4*)&Bs[r][c4] = *(const float4*)&W[(k0 + r) * HDIM + n0 + c4];
        }
        __syncthreads();
        #pragma unroll
        for (int kk = 0; kk < KT; ++kk) {
            const float4 av = *(const float4*)&As[kk][ty << 2];
            const float4 bv = *(const float4*)&Bs[kk][tx << 2];
            const float a[4] = {av.x, av.y, av.z, av.w};
            const float w4[4] = {bv.x, bv.y, bv.z, bv.w};
            #pragma unroll
            for (int i = 0; i < 4; ++i)
                #pragma unroll
                for (int j = 0; j < 4; ++j)
                    acc[i][j] += a[i] * w4[j];
        }
        __syncthreads();
    }
    float* Gp = G4 + s * GELEMS + b * (LSEQ * HDIM);
    #pragma unroll
    for (int i = 0; i < 4; ++i)
        *(float4*)&Gp[(m0 + (ty << 2) + i) * HDIM + n0 + (tx << 2)] =
            make_float4(acc[i][0], acc[i][1], acc[i][2], acc[i][3]);
}

// ---------------- K2: out += triu((ΣG)[b] @ H^T), tile 64i x 64j, micro 4x4, ksplit 8 ----------------
__global__ __launch_bounds__(256)
void pair(const float* __restrict__ G4, const float* __restrict__ hid,
          float* __restrict__ out) {
    __shared__ float Gs[KT][PADT];   // k-major: Gs[k][i']
    __shared__ float Hs[KT][PADT];   // k-major: Hs[k][j']
    const int b = blockIdx.y;
    const int s = blockIdx.z;                    // k-split slice (K=64 each)
    // map bid 0..35 -> (bi 0..7, bj bi..7): 64x64 tiles on an 8x8 grid, triu
    int rem = blockIdx.x, bi = 0;
    while (rem >= 8 - bi) { rem -= 8 - bi; ++bi; }
    const int bj = bi + rem;
    const int i0 = bi * 64, j0 = bj * 64;
    const int t  = threadIdx.x;
    const int tx = t & 15, ty = t >> 4;
    const float* Gb0 = G4 + 0 * GELEMS + b * (LSEQ * HDIM);
    const float* Gb1 = G4 + 1 * GELEMS + b * (LSEQ * HDIM);
    const float* Gb2 = G4 + 2 * GELEMS + b * (LSEQ * HDIM);
    const float* Gb3 = G4 + 3 * GELEMS + b * (LSEQ * HDIM);
    const float* Hb  = hid + b * (LSEQ * HDIM);

    float acc[4][4] = {};
    for (int k0 = s * 64; k0 < s * 64 + 64; k0 += KT) {
        #pragma unroll
        for (int l = 0; l < 2; ++l) {  // stage G = ΣG: 64 rows x 32 k, transpose
            const int idx = t + l * 256;
            const int r = idx >> 3, c4 = (idx & 7) << 2;
            const int off = (i0 + r) * HDIM + k0 + c4;
            float4 v0 = *(const float4*)&Gb0[off];
            float4 v1 = *(const float4*)&Gb1[off];
            float4 v2 = *(const float4*)&Gb2[off];
            float4 v3 = *(const float4*)&Gb3[off];
            Gs[c4 + 0][r] = (v0.x + v1.x) + (v2.x + v3.x);
            Gs[c4 + 1][r] = (v0.y + v1.y) + (v2.y + v3.y);
            Gs[c4 + 2][r] = (v0.z + v1.z) + (v2.z + v3.z);
            Gs[c4 + 3][r] = (v0.w + v1.w) + (v2.w + v3.w);
        }
        #pragma unroll
        for (int l = 0; l < 2; ++l) {  // stage H: 64 rows x 32 k, transpose
            const int idx = t + l * 256;
            const int r = idx >> 3, c4 = (idx & 7) << 2;
            float4 vh = *(const float4*)&Hb[(j0 + r) * HDIM + k0 + c4];
            Hs[c4 + 0][r] = vh.x; Hs[c4 + 1][r] = vh.y;
            Hs[c4 + 2][r] = vh.z; Hs[c4 + 3][r] = vh.w;
        }
        __syncthreads();
        #pragma unroll
        for (int kk = 0; kk < KT; ++kk) {
            const float4 gv = *(const float4*)&Gs[kk][ty << 2];
            const float4 hv = *(const float4*)&Hs[kk][tx << 2];
            const float g[4] = {gv.x, gv.y, gv.z, gv.w};
            const float h[4] = {hv.x, hv.y, hv.z, hv.w};
            #pragma unroll
            for (int i = 0; i < 4; ++i)
                #pragma unroll
                for (int j = 0; j < 4; ++j)
                    acc[i][j] += g[i] * h[j];
        }
        __syncthreads();
    }

    float* ob = out + b * NPAIR;
    #pragma unroll
    for (int ii = 0; ii < 4; ++ii) {
        const int i = i0 + (ty << 2) + ii;
        const int rowbase = (i * (1023 - i)) >> 1;
        const int jb = j0 + (tx << 2);
        #pragma unroll
        for (int jj = 0; jj < 4; ++jj) {
            const int j = jb + jj;
            if (j > i) atomicAdd(&ob[rowbase + j - i - 1], acc[ii][jj]);
        }
    }
}

extern "C" void kernel_launch(void* const* d_in, const int* in_sizes, int n_in,
                              void* d_out, int out_size, void* d_ws, size_t ws_size,
                              hipStream_t stream) {
    const float* hid  = (const float*)d_in[0];   // (2, 512, 512) f32
    const float* W    = (const float*)d_in[1];   // (1, 512, 512) f32
    const float* bias = (const float*)d_in[2];   // (1,) f32
    float* out = (float*)d_out;                  // (2, 130816) f32
    float* G4  = (float*)d_ws;                   // 4 x 2MB G partials

    gemm_g<<<dim3(8, 8, 8), 256, 0, stream>>>(hid, W, bias, G4, out);
    pair<<<dim3(36, 2, 8), 256, 0, stream>>>(G4, hid, out);
}

// Round 15
// 89.379 us; speedup vs baseline: 1.2804x; 1.2804x over previous
//
#include <hip/hip_runtime.h>

// ContactMapHead on MI355X — round 15: r13 structure, ATOMIC-FREE output path.
// r14 evidence: pair's 2.36M f32 atomicAdds = 35MB write-through RMW traffic
// (WRITE_SIZE counter), serializing the kernel at 43µs. Fix: each k-slice plain-
// stores to a private partial buffer P[s]; a reduce kernel sums + bias.
// logits[b, p(i,j)] = h_i^T W h_j + b, p(i,j) = i*(1023-i)/2 + (j-i-1).
//
//   K1 gemm_g:  G[s][b] = H[b] @ W (K-quarter s)          (1024 blk x 128 thr, r13-exact)
//   K2 pair:    P[s][b] = triu-partial(ΣG @ H^T, k-slice s) (576 blk x 256 thr, plain stores)
//   K3 reduce:  out = P0+P1+P2+P3 + bias                   (256 blk x 256 thr)

#define LSEQ 512
#define HDIM 512
#define NPAIR 130816     // 512*511/2
#define KT 32
#define PADA 36          // 36*4 = 144 B row stride (16B-aligned for b128)
#define PADH 68          // 68*4 = 272 B row stride (16B-aligned)
#define GELEMS (2 * LSEQ * HDIM)   // floats per G partial buffer (both batches)
#define PSTRIDE (2 * NPAIR)        // floats per pair-partial slice

// ---------------- K1: G[s][b] = H[b] @ W (K-quarter s) ----------------
__global__ __launch_bounds__(128)
void gemm_g(const float* __restrict__ hid, const float* __restrict__ W,
            float* __restrict__ G4) {
    __shared__ float As[KT][PADA];   // k-major: As[k][m']
    __shared__ float Bs[KT][64];     // k-major: Bs[k][n'] (natural from W rows)
    const int b  = blockIdx.z >> 2;          // batch
    const int s  = blockIdx.z & 3;           // K-quarter: k in [s*128, s*128+128)
    const int m0 = blockIdx.y * 32;
    const int n0 = blockIdx.x * 64;
    const int t  = threadIdx.x;
    const int tx = t & 15, ty = t >> 4;      // 16 x 8 thread grid, 4x4 micro
    const float* A = hid + b * (LSEQ * HDIM);

    float acc[4][4] = {};
    for (int k0 = s * 128; k0 < s * 128 + 128; k0 += KT) {
        #pragma unroll
        for (int l = 0; l < 2; ++l) {        // stage A: 32 rows x 32 k, transpose
            const int idx = t + l * 128;
            const int r = idx >> 3, c4 = (idx & 7) << 2;
            float4 va = *(const float4*)&A[(m0 + r) * HDIM + k0 + c4];
            As[c4 + 0][r] = va.x; As[c4 + 1][r] = va.y;
            As[c4 + 2][r] = va.z; As[c4 + 3][r] = va.w;
        }
        #pragma unroll
        for (int l = 0; l < 4; ++l) {        // stage B: 32 k-rows x 64 n
            const int idx = t + l * 128;
            const int r = idx >> 4, c4 = (idx & 15) << 2;
            *(float4*)&Bs[r][c4] = *(const float4*)&W[(k0 + r) * HDIM + n0 + c4];
        }
        __syncthreads();
        #pragma unroll
        for (int kk = 0; kk < KT; ++kk) {
            const float4 av = *(const float4*)&As[kk][ty << 2];
            const float4 bv = *(const float4*)&Bs[kk][tx << 2];
            const float a[4] = {av.x, av.y, av.z, av.w};
            const float w4[4] = {bv.x, bv.y, bv.z, bv.w};
            #pragma unroll
            for (int i = 0; i < 4; ++i)
                #pragma unroll
                for (int j = 0; j < 4; ++j)
                    acc[i][j] += a[i] * w4[j];
        }
        __syncthreads();
    }
    float* Gp = G4 + s * GELEMS + b * (LSEQ * HDIM);
    #pragma unroll
    for (int i = 0; i < 4; ++i)
        *(float4*)&Gp[(m0 + (ty << 2) + i) * HDIM + n0 + (tx << 2)] =
            make_float4(acc[i][0], acc[i][1], acc[i][2], acc[i][3]);
}

// ---------------- K2: P[s] = triu-partial((ΣG) @ H^T), tile 32i x 64j, plain stores ----------------
__global__ __launch_bounds__(256)
void pair(const float* __restrict__ G4, const float* __restrict__ hid,
          float* __restrict__ P) {
    __shared__ float Gs[KT][PADA];   // k-major: Gs[k][i']
    __shared__ float Hs[KT][PADH];   // k-major: Hs[k][j']
    const int b = blockIdx.y;
    const int s = blockIdx.z;                    // k-split slice (K=128 each)
    // map bid 0..71 -> (bi 0..15, bj (bi>>1)..7): 32-row i-tile, 64-col j-tile
    int rem = blockIdx.x, bi = 0;
    while (rem >= 8 - (bi >> 1)) { rem -= 8 - (bi >> 1); ++bi; }
    const int bj = (bi >> 1) + rem;
    const int i0 = bi * 32, j0 = bj * 64;
    const int t  = threadIdx.x;
    const int tx = t & 15, ty = t >> 4;
    const float* Gb0 = G4 + 0 * GELEMS + b * (LSEQ * HDIM);
    const float* Gb1 = G4 + 1 * GELEMS + b * (LSEQ * HDIM);
    const float* Gb2 = G4 + 2 * GELEMS + b * (LSEQ * HDIM);
    const float* Gb3 = G4 + 3 * GELEMS + b * (LSEQ * HDIM);
    const float* Hb  = hid + b * (LSEQ * HDIM);

    float acc[2][4] = {};
    for (int k0 = s * 128; k0 < s * 128 + 128; k0 += KT) {
        {   // stage G = G0+G1+G2+G3: 32 rows x 32 k, transpose to k-major
            const int r = t >> 3, c4 = (t & 7) << 2;
            const int off = (i0 + r) * HDIM + k0 + c4;
            float4 v0 = *(const float4*)&Gb0[off];
            float4 v1 = *(const float4*)&Gb1[off];
            float4 v2 = *(const float4*)&Gb2[off];
            float4 v3 = *(const float4*)&Gb3[off];
            Gs[c4 + 0][r] = (v0.x + v1.x) + (v2.x + v3.x);
            Gs[c4 + 1][r] = (v0.y + v1.y) + (v2.y + v3.y);
            Gs[c4 + 2][r] = (v0.z + v1.z) + (v2.z + v3.z);
            Gs[c4 + 3][r] = (v0.w + v1.w) + (v2.w + v3.w);
        }
        #pragma unroll
        for (int l = 0; l < 2; ++l) {  // stage H: 64 rows x 32 k, transpose
            const int idx = t + l * 256;
            const int r = idx >> 3, c4 = (idx & 7) << 2;
            float4 vh = *(const float4*)&Hb[(j0 + r) * HDIM + k0 + c4];
            Hs[c4 + 0][r] = vh.x; Hs[c4 + 1][r] = vh.y;
            Hs[c4 + 2][r] = vh.z; Hs[c4 + 3][r] = vh.w;
        }
        __syncthreads();
        #pragma unroll
        for (int kk = 0; kk < KT; ++kk) {
            const float2 gv = *(const float2*)&Gs[kk][ty << 1];
            const float4 hv = *(const float4*)&Hs[kk][tx << 2];
            const float g[2] = {gv.x, gv.y};
            const float h[4] = {hv.x, hv.y, hv.z, hv.w};
            #pragma unroll
            for (int i = 0; i < 2; ++i)
                #pragma unroll
                for (int j = 0; j < 4; ++j)
                    acc[i][j] += g[i] * h[j];
        }
        __syncthreads();
    }

    float* Pp = P + s * PSTRIDE + b * NPAIR;
    #pragma unroll
    for (int ii = 0; ii < 2; ++ii) {
        const int i = i0 + (ty << 1) + ii;
        const int rowbase = (i * (1023 - i)) >> 1;
        const int jb = j0 + (tx << 2);
        #pragma unroll
        for (int jj = 0; jj < 4; ++jj) {
            const int j = jb + jj;
            if (j > i) Pp[rowbase + j - i - 1] = acc[ii][jj];   // plain store, exactly once
        }
    }
}

// ---------------- K3: out = P0+P1+P2+P3 + bias ----------------
__global__ __launch_bounds__(256)
void reduce_bias(const float* __restrict__ P, const float* __restrict__ bias,
                 float* __restrict__ out) {
    const int i = blockIdx.x * 256 + threadIdx.x;    // float4 index over 2*NPAIR
    const int n4 = PSTRIDE / 4;                      // 65408
    if (i < n4) {
        const float4* P4 = (const float4*)P;
        float4 v0 = P4[i];
        float4 v1 = P4[i + 1 * n4];
        float4 v2 = P4[i + 2 * n4];
        float4 v3 = P4[i + 3 * n4];
        const float bb = bias[0];
        float4 r;
        r.x = (v0.x + v1.x) + (v2.x + v3.x) + bb;
        r.y = (v0.y + v1.y) + (v2.y + v3.y) + bb;
        r.z = (v0.z + v1.z) + (v2.z + v3.z) + bb;
        r.w = (v0.w + v1.w) + (v2.w + v3.w) + bb;
        ((float4*)out)[i] = r;
    }
}

extern "C" void kernel_launch(void* const* d_in, const int* in_sizes, int n_in,
                              void* d_out, int out_size, void* d_ws, size_t ws_size,
                              hipStream_t stream) {
    const float* hid  = (const float*)d_in[0];   // (2, 512, 512) f32
    const float* W    = (const float*)d_in[1];   // (1, 512, 512) f32
    const float* bias = (const float*)d_in[2];   // (1,) f32
    float* out = (float*)d_out;                  // (2, 130816) f32
    float* G4  = (float*)d_ws;                          // 4 x 2MB G partials
    float* P   = (float*)d_ws + 4 * GELEMS;             // 4 x 1.05MB pair partials

    gemm_g<<<dim3(8, 16, 8), 128, 0, stream>>>(hid, W, G4);
    pair<<<dim3(72, 2, 4), 256, 0, stream>>>(G4, hid, P);
    reduce_bias<<<256, 256, 0, stream>>>(P, bias, out);
}

// Round 16
// 87.437 us; speedup vs baseline: 1.3088x; 1.0222x over previous
//
#include <hip/hip_runtime.h>

// ContactMapHead on MI355X — round 16: bf16x3 MFMA for the G-GEMM (pair/reduce
// unchanged from r15-verified). f32 VALU FMA floor (~3.5µs) is the largest
// remaining term; CDNA4 has no fp32 MFMA, so split H,W into bf16 hi+lo and
// compute G ~= Hh*Wh + Hh*Wl + Hl*Wh on the matrix pipe (error ~2^-16 rel).
// logits[b, p(i,j)] = h_i^T W h_j + b, p(i,j) = i*(1023-i)/2 + (j-i-1).
//
//   K1 gemm_mfma: G[s][b] = H[b] @ W (K-quarter s)   (512 blk x 256 thr, 64x64 tile,
//                 4 waves = 2x2 32x32 quadrants, mfma_f32_16x16x32_bf16 x3 passes)
//   K2 pair:      P[s][b] = triu-partial(SumG @ H^T)  (576 blk x 256 thr, r15-exact)
//   K3 reduce:    out = P0+P1+P2+P3 + bias            (256 blk x 256 thr, r15-exact)

#define LSEQ 512
#define HDIM 512
#define NPAIR 130816     // 512*511/2
#define KT 32
#define PADA 36          // f32 LDS row stride for pair (16B-aligned)
#define PADH 68
#define LDSP 40          // shorts per bf16 LDS row: 80 B (16B-aligned, 2-way banks)
#define GELEMS (2 * LSEQ * HDIM)
#define PSTRIDE (2 * NPAIR)

typedef __attribute__((ext_vector_type(8))) short bf16x8;
typedef __attribute__((ext_vector_type(4))) short bf16x4;
typedef __attribute__((ext_vector_type(4))) float f32x4;

__device__ __forceinline__ void split2(float f, short& hi, short& lo) {
    unsigned u = __float_as_uint(f);
    hi = (short)(u >> 16);                                  // bf16 truncate
    float hif = __uint_as_float(u & 0xffff0000u);
    lo = (short)(__float_as_uint(f - hif) >> 16);           // residual as bf16
}

// ---------------- K1: G[s][b] = H[b] @ W via bf16x3 MFMA ----------------
__global__ __launch_bounds__(256)
void gemm_mfma(const float* __restrict__ hid, const float* __restrict__ W,
               float* __restrict__ G4) {
    __shared__ short Ah[64][LDSP], Al[64][LDSP];   // H tile, row-major [m][k]
    __shared__ short Bh[64][LDSP], Bl[64][LDSP];   // W tile TRANSPOSED [n][k]
    const int b  = blockIdx.z >> 2;
    const int s  = blockIdx.z & 3;           // K-quarter
    const int m0 = blockIdx.y * 64;
    const int n0 = blockIdx.x * 64;
    const int t    = threadIdx.x;
    const int lane = t & 63, w = t >> 6;
    const int wm = w >> 1, wn = w & 1;       // wave's 32x32 quadrant
    const float* A = hid + b * (LSEQ * HDIM);

    f32x4 acc00 = {}, acc01 = {}, acc10 = {}, acc11 = {};

    for (int k0 = s * 128; k0 < s * 128 + 128; k0 += KT) {
        #pragma unroll
        for (int l = 0; l < 2; ++l) {        // stage H tile: 64 rows x 32 k
            const int idx = t + l * 256;
            const int r = idx >> 3, c4 = (idx & 7) << 2;
            float4 v = *(const float4*)&A[(m0 + r) * HDIM + k0 + c4];
            short h0, h1, h2, h3, l0, l1, l2, l3;
            split2(v.x, h0, l0); split2(v.y, h1, l1);
            split2(v.z, h2, l2); split2(v.w, h3, l3);
            *(bf16x4*)&Ah[r][c4] = (bf16x4){h0, h1, h2, h3};
            *(bf16x4*)&Al[r][c4] = (bf16x4){l0, l1, l2, l3};
        }
        #pragma unroll
        for (int l = 0; l < 2; ++l) {        // stage W tile transposed: [n][k]
            const int idx = t + l * 256;
            const int kr = idx >> 4, c4 = (idx & 15) << 2;
            float4 v = *(const float4*)&W[(k0 + kr) * HDIM + n0 + c4];
            short h, lo;
            split2(v.x, h, lo); Bh[c4 + 0][kr] = h; Bl[c4 + 0][kr] = lo;
            split2(v.y, h, lo); Bh[c4 + 1][kr] = h; Bl[c4 + 1][kr] = lo;
            split2(v.z, h, lo); Bh[c4 + 2][kr] = h; Bl[c4 + 2][kr] = lo;
            split2(v.w, h, lo); Bh[c4 + 3][kr] = h; Bl[c4 + 3][kr] = lo;
        }
        __syncthreads();

        // fragment reads: A[row=lane&15][k=(lane>>4)*8+j], B[k][col=lane&15]
        const int fr   = lane & 15;
        const int koff = (lane >> 4) << 3;
        bf16x8 ah0 = *(const bf16x8*)&Ah[wm * 32 + fr     ][koff];
        bf16x8 ah1 = *(const bf16x8*)&Ah[wm * 32 + 16 + fr][koff];
        bf16x8 al0 = *(const bf16x8*)&Al[wm * 32 + fr     ][koff];
        bf16x8 al1 = *(const bf16x8*)&Al[wm * 32 + 16 + fr][koff];
        bf16x8 bh0 = *(const bf16x8*)&Bh[wn * 32 + fr     ][koff];
        bf16x8 bh1 = *(const bf16x8*)&Bh[wn * 32 + 16 + fr][koff];
        bf16x8 bl0 = *(const bf16x8*)&Bl[wn * 32 + fr     ][koff];
        bf16x8 bl1 = *(const bf16x8*)&Bl[wn * 32 + 16 + fr][koff];

        // pass hh
        acc00 = __builtin_amdgcn_mfma_f32_16x16x32_bf16(ah0, bh0, acc00, 0, 0, 0);
        acc01 = __builtin_amdgcn_mfma_f32_16x16x32_bf16(ah0, bh1, acc01, 0, 0, 0);
        acc10 = __builtin_amdgcn_mfma_f32_16x16x32_bf16(ah1, bh0, acc10, 0, 0, 0);
        acc11 = __builtin_amdgcn_mfma_f32_16x16x32_bf16(ah1, bh1, acc11, 0, 0, 0);
        // pass hl
        acc00 = __builtin_amdgcn_mfma_f32_16x16x32_bf16(ah0, bl0, acc00, 0, 0, 0);
        acc01 = __builtin_amdgcn_mfma_f32_16x16x32_bf16(ah0, bl1, acc01, 0, 0, 0);
        acc10 = __builtin_amdgcn_mfma_f32_16x16x32_bf16(ah1, bl0, acc10, 0, 0, 0);
        acc11 = __builtin_amdgcn_mfma_f32_16x16x32_bf16(ah1, bl1, acc11, 0, 0, 0);
        // pass lh
        acc00 = __builtin_amdgcn_mfma_f32_16x16x32_bf16(al0, bh0, acc00, 0, 0, 0);
        acc01 = __builtin_amdgcn_mfma_f32_16x16x32_bf16(al0, bh1, acc01, 0, 0, 0);
        acc10 = __builtin_amdgcn_mfma_f32_16x16x32_bf16(al1, bh0, acc10, 0, 0, 0);
        acc11 = __builtin_amdgcn_mfma_f32_16x16x32_bf16(al1, bh1, acc11, 0, 0, 0);

        __syncthreads();
    }

    // epilogue: D[row=(lane>>4)*4+r][col=lane&15] per 16x16 fragment
    float* Gp = G4 + s * GELEMS + b * (LSEQ * HDIM);
    const int drow = (lane >> 4) << 2;
    const int dcol = lane & 15;
    #pragma unroll
    for (int r = 0; r < 4; ++r) {
        const int row0 = m0 + wm * 32 + drow + r;
        const int col0 = n0 + wn * 32 + dcol;
        Gp[(row0     ) * HDIM + col0     ] = acc00[r];
        Gp[(row0     ) * HDIM + col0 + 16] = acc01[r];
        Gp[(row0 + 16) * HDIM + col0     ] = acc10[r];
        Gp[(row0 + 16) * HDIM + col0 + 16] = acc11[r];
    }
}

// ---------------- K2: P[s] = triu-partial((SumG) @ H^T)  (r15-exact) ----------------
__global__ __launch_bounds__(256)
void pair(const float* __restrict__ G4, const float* __restrict__ hid,
          float* __restrict__ P) {
    __shared__ float Gs[KT][PADA];
    __shared__ float Hs[KT][PADH];
    const int b = blockIdx.y;
    const int s = blockIdx.z;
    int rem = blockIdx.x, bi = 0;
    while (rem >= 8 - (bi >> 1)) { rem -= 8 - (bi >> 1); ++bi; }
    const int bj = (bi >> 1) + rem;
    const int i0 = bi * 32, j0 = bj * 64;
    const int t  = threadIdx.x;
    const int tx = t & 15, ty = t >> 4;
    const float* Gb0 = G4 + 0 * GELEMS + b * (LSEQ * HDIM);
    const float* Gb1 = G4 + 1 * GELEMS + b * (LSEQ * HDIM);
    const float* Gb2 = G4 + 2 * GELEMS + b * (LSEQ * HDIM);
    const float* Gb3 = G4 + 3 * GELEMS + b * (LSEQ * HDIM);
    const float* Hb  = hid + b * (LSEQ * HDIM);

    float acc[2][4] = {};
    for (int k0 = s * 128; k0 < s * 128 + 128; k0 += KT) {
        {
            const int r = t >> 3, c4 = (t & 7) << 2;
            const int off = (i0 + r) * HDIM + k0 + c4;
            float4 v0 = *(const float4*)&Gb0[off];
            float4 v1 = *(const float4*)&Gb1[off];
            float4 v2 = *(const float4*)&Gb2[off];
            float4 v3 = *(const float4*)&Gb3[off];
            Gs[c4 + 0][r] = (v0.x + v1.x) + (v2.x + v3.x);
            Gs[c4 + 1][r] = (v0.y + v1.y) + (v2.y + v3.y);
            Gs[c4 + 2][r] = (v0.z + v1.z) + (v2.z + v3.z);
            Gs[c4 + 3][r] = (v0.w + v1.w) + (v2.w + v3.w);
        }
        #pragma unroll
        for (int l = 0; l < 2; ++l) {
            const int idx = t + l * 256;
            const int r = idx >> 3, c4 = (idx & 7) << 2;
            float4 vh = *(const float4*)&Hb[(j0 + r) * HDIM + k0 + c4];
            Hs[c4 + 0][r] = vh.x; Hs[c4 + 1][r] = vh.y;
            Hs[c4 + 2][r] = vh.z; Hs[c4 + 3][r] = vh.w;
        }
        __syncthreads();
        #pragma unroll
        for (int kk = 0; kk < KT; ++kk) {
            const float2 gv = *(const float2*)&Gs[kk][ty << 1];
            const float4 hv = *(const float4*)&Hs[kk][tx << 2];
            const float g[2] = {gv.x, gv.y};
            const float h[4] = {hv.x, hv.y, hv.z, hv.w};
            #pragma unroll
            for (int i = 0; i < 2; ++i)
                #pragma unroll
                for (int j = 0; j < 4; ++j)
                    acc[i][j] += g[i] * h[j];
        }
        __syncthreads();
    }

    float* Pp = P + s * PSTRIDE + b * NPAIR;
    #pragma unroll
    for (int ii = 0; ii < 2; ++ii) {
        const int i = i0 + (ty << 1) + ii;
        const int rowbase = (i * (1023 - i)) >> 1;
        const int jb = j0 + (tx << 2);
        #pragma unroll
        for (int jj = 0; jj < 4; ++jj) {
            const int j = jb + jj;
            if (j > i) Pp[rowbase + j - i - 1] = acc[ii][jj];
        }
    }
}

// ---------------- K3: out = P0+P1+P2+P3 + bias  (r15-exact) ----------------
__global__ __launch_bounds__(256)
void reduce_bias(const float* __restrict__ P, const float* __restrict__ bias,
                 float* __restrict__ out) {
    const int i = blockIdx.x * 256 + threadIdx.x;
    const int n4 = PSTRIDE / 4;
    if (i < n4) {
        const float4* P4 = (const float4*)P;
        float4 v0 = P4[i];
        float4 v1 = P4[i + 1 * n4];
        float4 v2 = P4[i + 2 * n4];
        float4 v3 = P4[i + 3 * n4];
        const float bb = bias[0];
        float4 r;
        r.x = (v0.x + v1.x) + (v2.x + v3.x) + bb;
        r.y = (v0.y + v1.y) + (v2.y + v3.y) + bb;
        r.z = (v0.z + v1.z) + (v2.z + v3.z) + bb;
        r.w = (v0.w + v1.w) + (v2.w + v3.w) + bb;
        ((float4*)out)[i] = r;
    }
}

extern "C" void kernel_launch(void* const* d_in, const int* in_sizes, int n_in,
                              void* d_out, int out_size, void* d_ws, size_t ws_size,
                              hipStream_t stream) {
    const float* hid  = (const float*)d_in[0];   // (2, 512, 512) f32
    const float* W    = (const float*)d_in[1];   // (1, 512, 512) f32
    const float* bias = (const float*)d_in[2];   // (1,) f32
    float* out = (float*)d_out;                  // (2, 130816) f32
    float* G4  = (float*)d_ws;                          // 4 x 2MB G partials
    float* P   = (float*)d_ws + 4 * GELEMS;             // 4 x 1.05MB pair partials

    gemm_mfma<<<dim3(8, 8, 8), 256, 0, stream>>>(hid, W, G4);
    pair<<<dim3(72, 2, 4), 256, 0, stream>>>(G4, hid, P);
    reduce_bias<<<256, 256, 0, stream>>>(P, bias, out);
}

// Round 17
// 84.558 us; speedup vs baseline: 1.3534x; 1.0341x over previous
//
#include <hip/hip_runtime.h>

// ContactMapHead on MI355X — round 17: bf16x3 MFMA for BOTH GEMMs + RN splits.
// r16 verified the MFMA fragment layouts and bought 2µs on gemm; pair (3.5µs,
// f32 VALU) is now the biggest term. S = G*H^T needs NO transposed staging
// (B-operand [col][k] == H row-major). split2 upgraded truncate -> RN.
// logits[b, p(i,j)] = h_i^T W h_j + b, p(i,j) = i*(1023-i)/2 + (j-i-1).
//
//   K1 gemm_mfma: G[s][b] = H[b] @ W (K-quarter s)    (512 blk x 256 thr, r16 + RN)
//   K2 pair_mfma: P[s][b] = triu-partial(SumG @ H^T)  (576 blk x 256 thr, bf16x3 MFMA)
//   K3 reduce:    out = P0+P1+P2+P3 + bias            (256 blk x 256 thr, r15-exact)

#define LSEQ 512
#define HDIM 512
#define NPAIR 130816     // 512*511/2
#define KT 32
#define LDSP 40          // shorts per bf16 LDS row: 80 B (16B-aligned)
#define GELEMS (2 * LSEQ * HDIM)
#define PSTRIDE (2 * NPAIR)

typedef __attribute__((ext_vector_type(8))) short bf16x8;
typedef __attribute__((ext_vector_type(4))) short bf16x4;
typedef __attribute__((ext_vector_type(4))) float f32x4;

__device__ __forceinline__ short bf16rn(float f) {
    unsigned u = __float_as_uint(f);
    return (short)((u + 0x7fffu + ((u >> 16) & 1u)) >> 16);   // round-to-nearest-even
}
__device__ __forceinline__ void split2(float f, short& hi, short& lo) {
    hi = bf16rn(f);
    float hif = __uint_as_float(((unsigned)(unsigned short)hi) << 16);
    lo = bf16rn(f - hif);
}

// ---------------- K1: G[s][b] = H[b] @ W via bf16x3 MFMA (r16 + RN) ----------------
__global__ __launch_bounds__(256)
void gemm_mfma(const float* __restrict__ hid, const float* __restrict__ W,
               float* __restrict__ G4) {
    __shared__ short Ah[64][LDSP], Al[64][LDSP];   // H tile, row-major [m][k]
    __shared__ short Bh[64][LDSP], Bl[64][LDSP];   // W tile TRANSPOSED [n][k]
    const int b  = blockIdx.z >> 2;
    const int s  = blockIdx.z & 3;           // K-quarter
    const int m0 = blockIdx.y * 64;
    const int n0 = blockIdx.x * 64;
    const int t    = threadIdx.x;
    const int lane = t & 63, w = t >> 6;
    const int wm = w >> 1, wn = w & 1;       // wave's 32x32 quadrant
    const float* A = hid + b * (LSEQ * HDIM);

    f32x4 acc00 = {}, acc01 = {}, acc10 = {}, acc11 = {};

    for (int k0 = s * 128; k0 < s * 128 + 128; k0 += KT) {
        #pragma unroll
        for (int l = 0; l < 2; ++l) {        // stage H tile: 64 rows x 32 k
            const int idx = t + l * 256;
            const int r = idx >> 3, c4 = (idx & 7) << 2;
            float4 v = *(const float4*)&A[(m0 + r) * HDIM + k0 + c4];
            short h0, h1, h2, h3, l0, l1, l2, l3;
            split2(v.x, h0, l0); split2(v.y, h1, l1);
            split2(v.z, h2, l2); split2(v.w, h3, l3);
            *(bf16x4*)&Ah[r][c4] = (bf16x4){h0, h1, h2, h3};
            *(bf16x4*)&Al[r][c4] = (bf16x4){l0, l1, l2, l3};
        }
        #pragma unroll
        for (int l = 0; l < 2; ++l) {        // stage W tile transposed: [n][k]
            const int idx = t + l * 256;
            const int kr = idx >> 4, c4 = (idx & 15) << 2;
            float4 v = *(const float4*)&W[(k0 + kr) * HDIM + n0 + c4];
            short h, lo;
            split2(v.x, h, lo); Bh[c4 + 0][kr] = h; Bl[c4 + 0][kr] = lo;
            split2(v.y, h, lo); Bh[c4 + 1][kr] = h; Bl[c4 + 1][kr] = lo;
            split2(v.z, h, lo); Bh[c4 + 2][kr] = h; Bl[c4 + 2][kr] = lo;
            split2(v.w, h, lo); Bh[c4 + 3][kr] = h; Bl[c4 + 3][kr] = lo;
        }
        __syncthreads();

        const int fr   = lane & 15;
        const int koff = (lane >> 4) << 3;
        bf16x8 ah0 = *(const bf16x8*)&Ah[wm * 32 + fr     ][koff];
        bf16x8 ah1 = *(const bf16x8*)&Ah[wm * 32 + 16 + fr][koff];
        bf16x8 al0 = *(const bf16x8*)&Al[wm * 32 + fr     ][koff];
        bf16x8 al1 = *(const bf16x8*)&Al[wm * 32 + 16 + fr][koff];
        bf16x8 bh0 = *(const bf16x8*)&Bh[wn * 32 + fr     ][koff];
        bf16x8 bh1 = *(const bf16x8*)&Bh[wn * 32 + 16 + fr][koff];
        bf16x8 bl0 = *(const bf16x8*)&Bl[wn * 32 + fr     ][koff];
        bf16x8 bl1 = *(const bf16x8*)&Bl[wn * 32 + 16 + fr][koff];

        acc00 = __builtin_amdgcn_mfma_f32_16x16x32_bf16(ah0, bh0, acc00, 0, 0, 0);
        acc01 = __builtin_amdgcn_mfma_f32_16x16x32_bf16(ah0, bh1, acc01, 0, 0, 0);
        acc10 = __builtin_amdgcn_mfma_f32_16x16x32_bf16(ah1, bh0, acc10, 0, 0, 0);
        acc11 = __builtin_amdgcn_mfma_f32_16x16x32_bf16(ah1, bh1, acc11, 0, 0, 0);
        acc00 = __builtin_amdgcn_mfma_f32_16x16x32_bf16(ah0, bl0, acc00, 0, 0, 0);
        acc01 = __builtin_amdgcn_mfma_f32_16x16x32_bf16(ah0, bl1, acc01, 0, 0, 0);
        acc10 = __builtin_amdgcn_mfma_f32_16x16x32_bf16(ah1, bl0, acc10, 0, 0, 0);
        acc11 = __builtin_amdgcn_mfma_f32_16x16x32_bf16(ah1, bl1, acc11, 0, 0, 0);
        acc00 = __builtin_amdgcn_mfma_f32_16x16x32_bf16(al0, bh0, acc00, 0, 0, 0);
        acc01 = __builtin_amdgcn_mfma_f32_16x16x32_bf16(al0, bh1, acc01, 0, 0, 0);
        acc10 = __builtin_amdgcn_mfma_f32_16x16x32_bf16(al1, bh0, acc10, 0, 0, 0);
        acc11 = __builtin_amdgcn_mfma_f32_16x16x32_bf16(al1, bh1, acc11, 0, 0, 0);

        __syncthreads();
    }

    float* Gp = G4 + s * GELEMS + b * (LSEQ * HDIM);
    const int drow = (lane >> 4) << 2;
    const int dcol = lane & 15;
    #pragma unroll
    for (int r = 0; r < 4; ++r) {
        const int row0 = m0 + wm * 32 + drow + r;
        const int col0 = n0 + wn * 32 + dcol;
        Gp[(row0     ) * HDIM + col0     ] = acc00[r];
        Gp[(row0     ) * HDIM + col0 + 16] = acc01[r];
        Gp[(row0 + 16) * HDIM + col0     ] = acc10[r];
        Gp[(row0 + 16) * HDIM + col0 + 16] = acc11[r];
    }
}

// ---------------- K2: P[s] = triu-partial((SumG) @ H^T) via bf16x3 MFMA ----------------
// Tile 32i x 64j, 4 waves = 16x32 quadrants. No transposed staging needed:
// A-frag reads [row][k] (G rows), B-frag reads [col][k] (H rows, row-major).
__global__ __launch_bounds__(256)
void pair_mfma(const float* __restrict__ G4, const float* __restrict__ hid,
               float* __restrict__ P) {
    __shared__ short Ghs[32][LDSP], Gls[32][LDSP];   // SumG tile [i'][k] hi/lo
    __shared__ short Hhs[64][LDSP], Hls[64][LDSP];   // H tile [j'][k] hi/lo
    const int b = blockIdx.y;
    const int s = blockIdx.z;                    // k-split slice (K=128 each)
    int rem = blockIdx.x, bi = 0;
    while (rem >= 8 - (bi >> 1)) { rem -= 8 - (bi >> 1); ++bi; }
    const int bj = (bi >> 1) + rem;
    const int i0 = bi * 32, j0 = bj * 64;
    const int t    = threadIdx.x;
    const int lane = t & 63, w = t >> 6;
    const int wr = (w >> 1) << 4;                // wave row offset in tile (0/16)
    const int wc = (w & 1) << 5;                 // wave col offset (0/32)
    const float* Gb0 = G4 + 0 * GELEMS + b * (LSEQ * HDIM);
    const float* Gb1 = G4 + 1 * GELEMS + b * (LSEQ * HDIM);
    const float* Gb2 = G4 + 2 * GELEMS + b * (LSEQ * HDIM);
    const float* Gb3 = G4 + 3 * GELEMS + b * (LSEQ * HDIM);
    const float* Hb  = hid + b * (LSEQ * HDIM);

    f32x4 acc0 = {}, acc1 = {};

    for (int k0 = s * 128; k0 < s * 128 + 128; k0 += KT) {
        {   // stage SumG: 32 rows x 32 k, sum 4 partials + split (1 float4/thread)
            const int r = t >> 3, c4 = (t & 7) << 2;
            const int off = (i0 + r) * HDIM + k0 + c4;
            float4 v0 = *(const float4*)&Gb0[off];
            float4 v1 = *(const float4*)&Gb1[off];
            float4 v2 = *(const float4*)&Gb2[off];
            float4 v3 = *(const float4*)&Gb3[off];
            float g0 = (v0.x + v1.x) + (v2.x + v3.x);
            float g1 = (v0.y + v1.y) + (v2.y + v3.y);
            float g2 = (v0.z + v1.z) + (v2.z + v3.z);
            float g3 = (v0.w + v1.w) + (v2.w + v3.w);
            short h0, h1, h2, h3, l0, l1, l2, l3;
            split2(g0, h0, l0); split2(g1, h1, l1);
            split2(g2, h2, l2); split2(g3, h3, l3);
            *(bf16x4*)&Ghs[r][c4] = (bf16x4){h0, h1, h2, h3};
            *(bf16x4*)&Gls[r][c4] = (bf16x4){l0, l1, l2, l3};
        }
        #pragma unroll
        for (int l = 0; l < 2; ++l) {  // stage H: 64 rows x 32 k (2 float4/thread)
            const int idx = t + l * 256;
            const int r = idx >> 3, c4 = (idx & 7) << 2;
            float4 v = *(const float4*)&Hb[(j0 + r) * HDIM + k0 + c4];
            short h0, h1, h2, h3, l0, l1, l2, l3;
            split2(v.x, h0, l0); split2(v.y, h1, l1);
            split2(v.z, h2, l2); split2(v.w, h3, l3);
            *(bf16x4*)&Hhs[r][c4] = (bf16x4){h0, h1, h2, h3};
            *(bf16x4*)&Hls[r][c4] = (bf16x4){l0, l1, l2, l3};
        }
        __syncthreads();

        const int fr   = lane & 15;
        const int koff = (lane >> 4) << 3;
        bf16x8 ah  = *(const bf16x8*)&Ghs[wr + fr][koff];
        bf16x8 al  = *(const bf16x8*)&Gls[wr + fr][koff];
        bf16x8 bh0 = *(const bf16x8*)&Hhs[wc + fr     ][koff];
        bf16x8 bh1 = *(const bf16x8*)&Hhs[wc + 16 + fr][koff];
        bf16x8 bl0 = *(const bf16x8*)&Hls[wc + fr     ][koff];
        bf16x8 bl1 = *(const bf16x8*)&Hls[wc + 16 + fr][koff];

        acc0 = __builtin_amdgcn_mfma_f32_16x16x32_bf16(ah, bh0, acc0, 0, 0, 0);
        acc1 = __builtin_amdgcn_mfma_f32_16x16x32_bf16(ah, bh1, acc1, 0, 0, 0);
        acc0 = __builtin_amdgcn_mfma_f32_16x16x32_bf16(ah, bl0, acc0, 0, 0, 0);
        acc1 = __builtin_amdgcn_mfma_f32_16x16x32_bf16(ah, bl1, acc1, 0, 0, 0);
        acc0 = __builtin_amdgcn_mfma_f32_16x16x32_bf16(al, bh0, acc0, 0, 0, 0);
        acc1 = __builtin_amdgcn_mfma_f32_16x16x32_bf16(al, bh1, acc1, 0, 0, 0);

        __syncthreads();
    }

    // epilogue: D[row=(lane>>4)*4+r][col=lane&15]; store with triu predicate
    float* Pp = P + s * PSTRIDE + b * NPAIR;
    const int drow = (lane >> 4) << 2;
    const int dcol = lane & 15;
    #pragma unroll
    for (int r = 0; r < 4; ++r) {
        const int i = i0 + wr + drow + r;
        const int rowbase = (i * (1023 - i)) >> 1;
        const int jA = j0 + wc + dcol;
        const int jB = jA + 16;
        if (jA > i) Pp[rowbase + jA - i - 1] = acc0[r];
        if (jB > i) Pp[rowbase + jB - i - 1] = acc1[r];
    }
}

// ---------------- K3: out = P0+P1+P2+P3 + bias  (r15-exact) ----------------
__global__ __launch_bounds__(256)
void reduce_bias(const float* __restrict__ P, const float* __restrict__ bias,
                 float* __restrict__ out) {
    const int i = blockIdx.x * 256 + threadIdx.x;
    const int n4 = PSTRIDE / 4;
    if (i < n4) {
        const float4* P4 = (const float4*)P;
        float4 v0 = P4[i];
        float4 v1 = P4[i + 1 * n4];
        float4 v2 = P4[i + 2 * n4];
        float4 v3 = P4[i + 3 * n4];
        const float bb = bias[0];
        float4 r;
        r.x = (v0.x + v1.x) + (v2.x + v3.x) + bb;
        r.y = (v0.y + v1.y) + (v2.y + v3.y) + bb;
        r.z = (v0.z + v1.z) + (v2.z + v3.z) + bb;
        r.w = (v0.w + v1.w) + (v2.w + v3.w) + bb;
        ((float4*)out)[i] = r;
    }
}

extern "C" void kernel_launch(void* const* d_in, const int* in_sizes, int n_in,
                              void* d_out, int out_size, void* d_ws, size_t ws_size,
                              hipStream_t stream) {
    const float* hid  = (const float*)d_in[0];   // (2, 512, 512) f32
    const float* W    = (const float*)d_in[1];   // (1, 512, 512) f32
    const float* bias = (const float*)d_in[2];   // (1,) f32
    float* out = (float*)d_out;                  // (2, 130816) f32
    float* G4  = (float*)d_ws;                          // 4 x 2MB G partials
    float* P   = (float*)d_ws + 4 * GELEMS;             // 4 x 1.05MB pair partials

    gemm_mfma<<<dim3(8, 8, 8), 256, 0, stream>>>(hid, W, G4);
    pair_mfma<<<dim3(72, 2, 4), 256, 0, stream>>>(G4, hid, P);
    reduce_bias<<<256, 256, 0, stream>>>(P, bias, out);
}